// Round 1
// baseline (7008.040 us; speedup 1.0000x reference)
//
#include <hip/hip_runtime.h>
#include <hip/hip_bf16.h>
#include <math.h>

// Problem constants (fixed by the reference)
#define T_LEN 4096
#define EMBD 1024
#define DH 128
#define NHASH 8
#define NHEADS 8
#define BKT 64          // bucket size == n_buckets == n_bins
#define NBINS 64
#define BB 16           // B = batch(2) * heads(8)

// ------------------------------------------------------------------
// K1: qk = x @ w_qk in f64 (hash path must be near-exact), write qk f32
//     (merged-head layout), then LSH hash: rotated = qk64 . rot (f64),
//     bucket = argmax(concat[rotated, -rotated]) with first-index ties.
// One block per token row (8192 blocks, 256 threads).
// ------------------------------------------------------------------
__global__ __launch_bounds__(256) void k_qk_hash(
    const float* __restrict__ x, const float* __restrict__ wqk,
    const float* __restrict__ rot, float* __restrict__ qk_m,
    unsigned* __restrict__ bucketArr)
{
    __shared__ float xs[EMBD];
    __shared__ double qs[EMBD];
    const int row = blockIdx.x;           // b*4096 + t
    const int b = row >> 12, t = row & 4095;
    const int tid = threadIdx.x;

    reinterpret_cast<float4*>(xs)[tid] =
        reinterpret_cast<const float4*>(x + (size_t)row * EMBD)[tid];
    __syncthreads();

    // columns 4*tid .. 4*tid+3, f64 accumulate (f32*f32 exact in f64)
    double a0 = 0, a1 = 0, a2 = 0, a3 = 0;
    {
        const float* wp = wqk + 4 * tid;
        #pragma unroll 4
        for (int e = 0; e < EMBD; ++e) {
            float4 w4 = *reinterpret_cast<const float4*>(wp + (size_t)e * EMBD);
            double xe = (double)xs[e];
            a0 = fma(xe, (double)w4.x, a0);
            a1 = fma(xe, (double)w4.y, a1);
            a2 = fma(xe, (double)w4.z, a2);
            a3 = fma(xe, (double)w4.w, a3);
        }
    }
    qs[4 * tid + 0] = a0; qs[4 * tid + 1] = a1;
    qs[4 * tid + 2] = a2; qs[4 * tid + 3] = a3;
    {
        // merged-head layout: (B=b*8+h, t, d)
        int j = 4 * tid;
        int h = j >> 7, d = j & 127;
        float4 o;
        o.x = (float)a0; o.y = (float)a1; o.z = (float)a2; o.w = (float)a3;
        *reinterpret_cast<float4*>(
            qk_m + (((size_t)(b * NHEADS + h) * T_LEN + t) * DH + d)) = o;
    }
    __syncthreads();

    // hash: thread (r = tid>>5, i = tid&31) for each head hh
    const int r = tid >> 5, i = tid & 31;
    for (int hh = 0; hh < NHEADS; ++hh) {
        const double* q = qs + hh * DH;
        const float* rp = rot + r * 32 + i;   // rot[f][r][i] = rot[f*256 + r*32 + i]
        double acc = 0;
        #pragma unroll 8
        for (int f = 0; f < DH; ++f) acc = fma(q[f], (double)rp[(size_t)f * 256], acc);
        // local candidate over {rotated_i (idx i), -rotated_i (idx i+32)},
        // first-index tie rule (>= keeps idx i on exact tie / -0.0)
        double v; int idx;
        if (acc >= 0.0) { v = acc; idx = i; } else { v = -acc; idx = i + 32; }
        #pragma unroll
        for (int m = 1; m < 32; m <<= 1) {
            double ov = __shfl_xor(v, m);
            int oi = __shfl_xor(idx, m);
            if (ov > v || (ov == v && oi < idx)) { v = ov; idx = oi; }
        }
        if (i == 0)
            bucketArr[((size_t)(b * NHEADS + hh) * NHASH + r) * T_LEN + t] = (unsigned)idx;
    }
}

// ------------------------------------------------------------------
// K2: v = x @ w_v in f32, merged-head layout.
// ------------------------------------------------------------------
__global__ __launch_bounds__(256) void k_vproj(
    const float* __restrict__ x, const float* __restrict__ wv, float* __restrict__ v_m)
{
    __shared__ float xs[EMBD];
    const int row = blockIdx.x;
    const int b = row >> 12, t = row & 4095;
    const int tid = threadIdx.x;
    reinterpret_cast<float4*>(xs)[tid] =
        reinterpret_cast<const float4*>(x + (size_t)row * EMBD)[tid];
    __syncthreads();
    float a0 = 0, a1 = 0, a2 = 0, a3 = 0;
    const float* wp = wv + 4 * tid;
    #pragma unroll 4
    for (int e = 0; e < EMBD; ++e) {
        float4 w4 = *reinterpret_cast<const float4*>(wp + (size_t)e * EMBD);
        float xe = xs[e];
        a0 = fmaf(xe, w4.x, a0); a1 = fmaf(xe, w4.y, a1);
        a2 = fmaf(xe, w4.z, a2); a3 = fmaf(xe, w4.w, a3);
    }
    int j = 4 * tid;
    int h = j >> 7, d = j & 127;
    float4 o; o.x = a0; o.y = a1; o.z = a2; o.w = a3;
    *reinterpret_cast<float4*>(
        v_m + (((size_t)(b * NHEADS + h) * T_LEN + t) * DH + d)) = o;
}

// ------------------------------------------------------------------
// K3: stable counting sort per (B, hash-round): 4096 tokens by bucket(64),
// ties broken by position. st[B][r][sorted_pos] = token index.
// One block (64 threads) per (B, r) = 128 blocks.
// ------------------------------------------------------------------
__global__ __launch_bounds__(64) void k_sort(
    const unsigned* __restrict__ bucketArr, unsigned* __restrict__ st)
{
    __shared__ unsigned short bkt[T_LEN];
    __shared__ unsigned hist[64][64];     // [chunk][bucket]
    __shared__ unsigned bstart[64];
    const int B = blockIdx.x >> 3, r = blockIdx.x & 7;
    const unsigned* src = bucketArr + ((size_t)B * NHASH + r) * T_LEN;
    const int tid = threadIdx.x;

    for (int k = tid; k < T_LEN; k += 64) bkt[k] = (unsigned short)src[k];
    for (int k = tid; k < 64 * 64; k += 64) (&hist[0][0])[k] = 0;
    __syncthreads();
    {   // chunk tid owns tokens [tid*64, tid*64+64)
        const int base = tid * 64;
        for (int k = 0; k < 64; ++k) hist[tid][bkt[base + k]]++;
    }
    __syncthreads();
    {   // bucket totals (thread owns bucket tid)
        unsigned tot = 0;
        for (int c = 0; c < 64; ++c) tot += hist[c][tid];
        bstart[tid] = tot;
    }
    __syncthreads();
    if (tid == 0) {
        unsigned run = 0;
        for (int q = 0; q < 64; ++q) { unsigned c = bstart[q]; bstart[q] = run; run += c; }
    }
    __syncthreads();
    {   // per-(chunk,bucket) start offsets, in place
        unsigned run = bstart[tid];
        for (int c = 0; c < 64; ++c) { unsigned h = hist[c][tid]; hist[c][tid] = run; run += h; }
    }
    __syncthreads();
    {   // stable scatter: thread owns chunk tid, sequential within chunk
        unsigned* dst = st + ((size_t)B * NHASH + r) * T_LEN;
        const int base = tid * 64;
        for (int k = 0; k < 64; ++k) {
            unsigned bb2 = bkt[base + k];
            unsigned p = hist[tid][bb2]++;
            dst[p] = (unsigned)(base + k);
        }
    }
}

// ------------------------------------------------------------------
// K4 (template): per-bin attention. PHASE 0: dots + per-round logsumexp
// -> logitsArr[B][r][token]. PHASE 1: recompute dots, p = exp(dot - LSE_tok)
// (folds the per-round lse + cross-round softmax weight exactly),
// PV, atomicAdd into attn[B][token][d].
// Bin = 64 queries; keys = own bin + look-one-back bin (bin0 -> bin1) = 128.
// 8192 blocks (B*8*64), 256 threads. ~130 KB static LDS (1 block/CU).
// ------------------------------------------------------------------
template <int PHASE>
__global__ __launch_bounds__(256) void k_attn(
    const float* __restrict__ qk_m, const float* __restrict__ v_m,
    const unsigned* __restrict__ st,
    float* __restrict__ logitsArr, const float* __restrict__ LSE,
    float* __restrict__ attn)
{
    __shared__ float qsT[128 * 65];                 // q transposed [d][i], stride 65; probs [j][i] in PHASE 1
    __shared__ float ksm[128 * 129];                // k rows [j][d], stride 129 (bank pad)
    __shared__ __hip_bfloat16 vsm[128 * 128];       // v rows bf16 (PHASE 1)
    __shared__ int qtok[64];
    __shared__ int ktok[128];
    __shared__ float lse_s[64];

    const int tid = threadIdx.x;
    const int c = blockIdx.x & 63;
    const int r = (blockIdx.x >> 6) & 7;
    const int B = blockIdx.x >> 9;
    const unsigned* stp = st + ((size_t)B * NHASH + r) * T_LEN;

    if (tid < 64) {
        qtok[tid] = (int)stp[c * 64 + tid];
    } else if (tid < 192) {
        int j = tid - 64;
        int cc = (j < 64) ? c : (c == 0 ? 1 : c - 1);   // look_one_back
        ktok[j] = (int)stp[cc * 64 + (j & 63)];
    }
    __syncthreads();

    const float scale = 0.08838834764831845f;  // 128^-0.5
    for (int u = tid; u < 64 * DH; u += 256) {
        int i = u >> 7, d = u & 127;
        qsT[d * 65 + i] = qk_m[((size_t)B * T_LEN + qtok[i]) * DH + d] * scale;
    }
    for (int u = tid; u < 128 * DH; u += 256) {
        int j = u >> 7, d = u & 127;
        ksm[j * 129 + d] = qk_m[((size_t)B * T_LEN + ktok[j]) * DH + d];
    }
    if (PHASE == 1) {
        for (int u = tid; u < 128 * DH; u += 256) {
            int j = u >> 7, d = u & 127;
            vsm[j * 128 + d] = __float2bfloat16(v_m[((size_t)B * T_LEN + ktok[j]) * DH + d]);
        }
        if (tid < 64) lse_s[tid] = LSE[(size_t)B * T_LEN + qtok[tid]];
    }
    __syncthreads();

    // l2-normalize key rows (tf.math.l2_normalize, eps 1e-12)
    if (tid < 128) {
        float ss = 0.f;
        for (int d = 0; d < DH; ++d) { float kv = ksm[tid * 129 + d]; ss = fmaf(kv, kv, ss); }
        float rs = 1.0f / sqrtf(fmaxf(ss, 1e-12f));
        for (int d = 0; d < DH; ++d) ksm[tid * 129 + d] *= rs;
    }
    __syncthreads();

    // dots: thread (ig = tid>>4, jg = tid&15) owns i in ig*4..+3, j in jg*8..+7
    const int ig = tid >> 4, jg = tid & 15;
    float acc[4][8];
    #pragma unroll
    for (int a2 = 0; a2 < 4; ++a2)
        #pragma unroll
        for (int b2 = 0; b2 < 8; ++b2) acc[a2][b2] = 0.f;

    for (int d = 0; d < DH; ++d) {
        float qa[4], kb[8];
        #pragma unroll
        for (int a2 = 0; a2 < 4; ++a2) qa[a2] = qsT[d * 65 + ig * 4 + a2];
        #pragma unroll
        for (int b2 = 0; b2 < 8; ++b2) kb[b2] = ksm[(jg * 8 + b2) * 129 + d];
        #pragma unroll
        for (int a2 = 0; a2 < 4; ++a2)
            #pragma unroll
            for (int b2 = 0; b2 < 8; ++b2) acc[a2][b2] = fmaf(qa[a2], kb[b2], acc[a2][b2]);
    }
    // self-mask: token attending to itself -> exactly -1e5
    #pragma unroll
    for (int a2 = 0; a2 < 4; ++a2) {
        int itok = qtok[ig * 4 + a2];
        #pragma unroll
        for (int b2 = 0; b2 < 8; ++b2)
            if (itok == ktok[jg * 8 + b2]) acc[a2][b2] = -1e5f;
    }

    if constexpr (PHASE == 0) {
        // per-query logsumexp over 128 keys (reduce across 16 jg lanes)
        #pragma unroll
        for (int a2 = 0; a2 < 4; ++a2) {
            float m = acc[a2][0];
            #pragma unroll
            for (int b2 = 1; b2 < 8; ++b2) m = fmaxf(m, acc[a2][b2]);
            float s = 0.f;
            #pragma unroll
            for (int b2 = 0; b2 < 8; ++b2) s += expf(acc[a2][b2] - m);
            for (int w = 1; w < 16; w <<= 1) {
                float om = __shfl_xor(m, w);
                float os = __shfl_xor(s, w);
                float nm = fmaxf(m, om);
                s = s * expf(m - nm) + os * expf(om - nm);
                m = nm;
            }
            if (jg == 0)
                logitsArr[((size_t)B * NHASH + r) * T_LEN + qtok[ig * 4 + a2]] = m + logf(s);
        }
    } else {
        // probs folded with cross-round weight: p = exp(dot - LSE_token)
        __syncthreads();   // everyone done reading qsT before overwrite
        #pragma unroll
        for (int a2 = 0; a2 < 4; ++a2) {
            float lse = lse_s[ig * 4 + a2];
            #pragma unroll
            for (int b2 = 0; b2 < 8; ++b2) {
                float p = expf(acc[a2][b2] - lse);
                qsT[(jg * 8 + b2) * 65 + (ig * 4 + a2)] = p;   // probsT[j][i]
            }
        }
        __syncthreads();
        // PV: thread (ig2 = tid>>4 over i, dg = tid&15 over d)
        const int ig2 = tid >> 4, dg = tid & 15;
        float acc2[4][8];
        #pragma unroll
        for (int a2 = 0; a2 < 4; ++a2)
            #pragma unroll
            for (int b2 = 0; b2 < 8; ++b2) acc2[a2][b2] = 0.f;
        for (int j = 0; j < 128; ++j) {
            float pa[4], vb[8];
            #pragma unroll
            for (int a2 = 0; a2 < 4; ++a2) pa[a2] = qsT[j * 65 + ig2 * 4 + a2];
            #pragma unroll
            for (int b2 = 0; b2 < 8; ++b2) vb[b2] = __bfloat162float(vsm[j * 128 + dg * 8 + b2]);
            #pragma unroll
            for (int a2 = 0; a2 < 4; ++a2)
                #pragma unroll
                for (int b2 = 0; b2 < 8; ++b2) acc2[a2][b2] = fmaf(pa[a2], vb[b2], acc2[a2][b2]);
        }
        #pragma unroll
        for (int a2 = 0; a2 < 4; ++a2) {
            int tok = qtok[ig2 * 4 + a2];
            float* dstp = attn + ((size_t)B * T_LEN + tok) * DH + dg * 8;
            #pragma unroll
            for (int b2 = 0; b2 < 8; ++b2) atomicAdd(dstp + b2, acc2[a2][b2]);
        }
    }
}

// ------------------------------------------------------------------
// K5: LSE over the 8 hash rounds per (B, token).
// ------------------------------------------------------------------
__global__ __launch_bounds__(256) void k_lse(
    const float* __restrict__ logitsArr, float* __restrict__ LSE)
{
    int g = blockIdx.x * 256 + threadIdx.x;    // B*4096 + tok, 65536 total
    int B = g >> 12, tok = g & 4095;
    float l[NHASH];
    float m = -1e30f;
    #pragma unroll
    for (int r = 0; r < NHASH; ++r) {
        l[r] = logitsArr[((size_t)B * NHASH + r) * T_LEN + tok];
        m = fmaxf(m, l[r]);
    }
    float s = 0.f;
    #pragma unroll
    for (int r = 0; r < NHASH; ++r) s += expf(l[r] - m);
    LSE[g] = m + logf(s);
}

// ------------------------------------------------------------------
// K6: out = un-merge-heads(attn) @ w_out + b_out
// ------------------------------------------------------------------
__global__ __launch_bounds__(256) void k_out(
    const float* __restrict__ attn, const float* __restrict__ wout,
    const float* __restrict__ bout, float* __restrict__ out)
{
    __shared__ float as_[EMBD];
    const int row = blockIdx.x;
    const int b = row >> 12, t = row & 4095;
    const int tid = threadIdx.x;
    for (int u = tid; u < EMBD; u += 256) {
        int h = u >> 7, d = u & 127;
        as_[u] = attn[((size_t)(b * NHEADS + h) * T_LEN + t) * DH + d];
    }
    __syncthreads();
    float a0 = 0, a1 = 0, a2 = 0, a3 = 0;
    const float* wp = wout + 4 * tid;
    #pragma unroll 4
    for (int e = 0; e < EMBD; ++e) {
        float4 w4 = *reinterpret_cast<const float4*>(wp + (size_t)e * EMBD);
        float xe = as_[e];
        a0 = fmaf(xe, w4.x, a0); a1 = fmaf(xe, w4.y, a1);
        a2 = fmaf(xe, w4.z, a2); a3 = fmaf(xe, w4.w, a3);
    }
    int j = 4 * tid;
    float4 o;
    o.x = a0 + bout[j + 0]; o.y = a1 + bout[j + 1];
    o.z = a2 + bout[j + 2]; o.w = a3 + bout[j + 3];
    *reinterpret_cast<float4*>(out + (size_t)row * EMBD + j) = o;
}

// ------------------------------------------------------------------
extern "C" void kernel_launch(void* const* d_in, const int* in_sizes, int n_in,
                              void* d_out, int out_size, void* d_ws, size_t ws_size,
                              hipStream_t stream)
{
    const float* x    = (const float*)d_in[0];
    const float* wqk  = (const float*)d_in[1];
    const float* wv   = (const float*)d_in[2];
    const float* wout = (const float*)d_in[3];
    const float* bout = (const float*)d_in[4];
    const float* rot  = (const float*)d_in[5];
    float* out = (float*)d_out;

    // workspace layout (bytes):
    //   qk_m      f32 [16][4096][128]   33,554,432
    //   v_m       f32 [16][4096][128]   33,554,432
    //   attn      f32 [16][4096][128]   33,554,432
    //   bucketArr u32 [16][8][4096]      2,097,152
    //   st        u32 [16][8][4096]      2,097,152
    //   logits    f32 [16][8][4096]      2,097,152
    //   LSE       f32 [16][4096]           262,144
    char* ws = (char*)d_ws;
    float*    qk_m      = (float*)(ws);
    float*    v_m       = (float*)(ws + 33554432);
    float*    attn      = (float*)(ws + 67108864);
    unsigned* bucketArr = (unsigned*)(ws + 100663296);
    unsigned* st        = (unsigned*)(ws + 102760448);
    float*    logitsArr = (float*)(ws + 104857600);
    float*    LSE       = (float*)(ws + 106954752);

    hipMemsetAsync(attn, 0, 33554432, stream);

    k_qk_hash<<<8192, 256, 0, stream>>>(x, wqk, rot, qk_m, bucketArr);
    k_vproj<<<8192, 256, 0, stream>>>(x, wv, v_m);
    k_sort<<<128, 64, 0, stream>>>(bucketArr, st);
    k_attn<0><<<8192, 256, 0, stream>>>(qk_m, v_m, st, logitsArr, LSE, attn);
    k_lse<<<256, 256, 0, stream>>>(logitsArr, LSE);
    k_attn<1><<<8192, 256, 0, stream>>>(qk_m, v_m, st, logitsArr, LSE, attn);
    k_out<<<8192, 256, 0, stream>>>(attn, wout, bout, out);
}

// Round 8
// 5752.089 us; speedup vs baseline: 1.2183x; 1.2183x over previous
//
#include <hip/hip_runtime.h>
#include <hip/hip_bf16.h>
#include <math.h>

#define T_LEN 4096
#define EMBD 1024
#define DH 128
#define NHASH 8
#define NHEADS 8

typedef __attribute__((ext_vector_type(8))) short short8;
typedef __attribute__((ext_vector_type(16))) float f32x16;

// LDS swizzle: row-major [r][128] bf16, 16B-block XOR by (row&7) — G4 fix.
__device__ __forceinline__ int swz(int row, int col) {
    return (row << 7) + (col ^ ((row & 7) << 3));
}
__device__ __forceinline__ unsigned cvtpk(float lo, float hi) {
    unsigned r;
    asm("v_cvt_pk_bf16_f32 %0, %1, %2" : "=v"(r) : "v"(lo), "v"(hi));
    return r;
}
__device__ __forceinline__ float bfu_lo(unsigned u) {
    union { unsigned x; float f; } c; c.x = u << 16; return c.f;
}
__device__ __forceinline__ float bfu_hi(unsigned u) {
    union { unsigned x; float f; } c; c.x = u & 0xffff0000u; return c.f;
}
__device__ __forceinline__ float bfs2f(short s) {
    union { unsigned x; float f; } c; c.x = ((unsigned)(unsigned short)s) << 16; return c.f;
}

// ------------------------------------------------------------------
// K1: qk = x @ w_qk in f64 (hash path must be near-exact). Emits:
//   qkh/qkl: raw qk as exact hi/lo bf16 pair, rsn: 1/||qk||, buckets.
// ------------------------------------------------------------------
__global__ __launch_bounds__(256) void k_qk_hash(
    const float* __restrict__ x, const float* __restrict__ wqk,
    const float* __restrict__ rot, __hip_bfloat16* __restrict__ qkh,
    __hip_bfloat16* __restrict__ qkl, float* __restrict__ rsn,
    unsigned* __restrict__ bucketArr)
{
    __shared__ float xs[EMBD];
    __shared__ double qs[EMBD];
    const int row = blockIdx.x;           // b*4096 + t
    const int b = row >> 12, t = row & 4095;
    const int tid = threadIdx.x;

    reinterpret_cast<float4*>(xs)[tid] =
        reinterpret_cast<const float4*>(x + (size_t)row * EMBD)[tid];
    __syncthreads();

    double a0 = 0, a1 = 0, a2 = 0, a3 = 0;
    {
        const float* wp = wqk + 4 * tid;
        #pragma unroll 4
        for (int e = 0; e < EMBD; ++e) {
            float4 w4 = *reinterpret_cast<const float4*>(wp + (size_t)e * EMBD);
            double xe = (double)xs[e];
            a0 = fma(xe, (double)w4.x, a0);
            a1 = fma(xe, (double)w4.y, a1);
            a2 = fma(xe, (double)w4.z, a2);
            a3 = fma(xe, (double)w4.w, a3);
        }
    }
    qs[4 * tid + 0] = a0; qs[4 * tid + 1] = a1;
    qs[4 * tid + 2] = a2; qs[4 * tid + 3] = a3;

    float f0 = (float)a0, f1 = (float)a1, f2 = (float)a2, f3 = (float)a3;
    float ss = f0*f0 + f1*f1 + f2*f2 + f3*f3;
    #pragma unroll
    for (int m = 1; m < 32; m <<= 1) ss += __shfl_xor(ss, m);
    float rs = 1.0f / sqrtf(fmaxf(ss, 1e-12f));

    {
        int j = 4 * tid;
        int h = j >> 7, d = j & 127;
        size_t base = ((size_t)(b * NHEADS + h) * T_LEN + t) * DH + d;
        unsigned h01 = cvtpk(f0, f1), h23 = cvtpk(f2, f3);
        float l0 = f0 - bfu_lo(h01), l1 = f1 - bfu_hi(h01);
        float l2 = f2 - bfu_lo(h23), l3 = f3 - bfu_hi(h23);
        unsigned l01 = cvtpk(l0, l1), l23 = cvtpk(l2, l3);
        *reinterpret_cast<uint2*>(qkh + base) = make_uint2(h01, h23);
        *reinterpret_cast<uint2*>(qkl + base) = make_uint2(l01, l23);
        if ((tid & 31) == 0)
            rsn[(size_t)(b * NHEADS + h) * T_LEN + t] = rs;
    }
    __syncthreads();

    const int r = tid >> 5, i = tid & 31;
    for (int hh = 0; hh < NHEADS; ++hh) {
        const double* q = qs + hh * DH;
        const float* rp = rot + r * 32 + i;
        double acc = 0;
        #pragma unroll 8
        for (int f = 0; f < DH; ++f) acc = fma(q[f], (double)rp[(size_t)f * 256], acc);
        double v; int idx;
        if (acc >= 0.0) { v = acc; idx = i; } else { v = -acc; idx = i + 32; }
        #pragma unroll
        for (int m = 1; m < 32; m <<= 1) {
            double ov = __shfl_xor(v, m);
            int oi = __shfl_xor(idx, m);
            if (ov > v || (ov == v && oi < idx)) { v = ov; idx = oi; }
        }
        if (i == 0)
            bucketArr[((size_t)(b * NHEADS + hh) * NHASH + r) * T_LEN + t] = (unsigned)idx;
    }
}

// ------------------------------------------------------------------
// K2: v = x @ w_v in f32 -> v_bf16, merged-head layout.
// ------------------------------------------------------------------
__global__ __launch_bounds__(256) void k_vproj(
    const float* __restrict__ x, const float* __restrict__ wv,
    __hip_bfloat16* __restrict__ vb)
{
    __shared__ float xs[EMBD];
    const int row = blockIdx.x;
    const int b = row >> 12, t = row & 4095;
    const int tid = threadIdx.x;
    reinterpret_cast<float4*>(xs)[tid] =
        reinterpret_cast<const float4*>(x + (size_t)row * EMBD)[tid];
    __syncthreads();
    float a0 = 0, a1 = 0, a2 = 0, a3 = 0;
    const float* wp = wv + 4 * tid;
    #pragma unroll 4
    for (int e = 0; e < EMBD; ++e) {
        float4 w4 = *reinterpret_cast<const float4*>(wp + (size_t)e * EMBD);
        float xe = xs[e];
        a0 = fmaf(xe, w4.x, a0); a1 = fmaf(xe, w4.y, a1);
        a2 = fmaf(xe, w4.z, a2); a3 = fmaf(xe, w4.w, a3);
    }
    int j = 4 * tid;
    int h = j >> 7, d = j & 127;
    *reinterpret_cast<uint2*>(vb + ((size_t)(b * NHEADS + h) * T_LEN + t) * DH + d)
        = make_uint2(cvtpk(a0, a1), cvtpk(a2, a3));
}

// ------------------------------------------------------------------
// K3: stable counting sort per (B, hash-round) — unchanged (proven).
// ------------------------------------------------------------------
__global__ __launch_bounds__(64) void k_sort(
    const unsigned* __restrict__ bucketArr, unsigned* __restrict__ st)
{
    __shared__ unsigned short bkt[T_LEN];
    __shared__ unsigned hist[64][64];
    __shared__ unsigned bstart[64];
    const int B = blockIdx.x >> 3, r = blockIdx.x & 7;
    const unsigned* src = bucketArr + ((size_t)B * NHASH + r) * T_LEN;
    const int tid = threadIdx.x;

    for (int k = tid; k < T_LEN; k += 64) bkt[k] = (unsigned short)src[k];
    for (int k = tid; k < 64 * 64; k += 64) (&hist[0][0])[k] = 0;
    __syncthreads();
    {
        const int base = tid * 64;
        for (int k = 0; k < 64; ++k) hist[tid][bkt[base + k]]++;
    }
    __syncthreads();
    {
        unsigned tot = 0;
        for (int c = 0; c < 64; ++c) tot += hist[c][tid];
        bstart[tid] = tot;
    }
    __syncthreads();
    if (tid == 0) {
        unsigned run = 0;
        for (int q = 0; q < 64; ++q) { unsigned c = bstart[q]; bstart[q] = run; run += c; }
    }
    __syncthreads();
    {
        unsigned run = bstart[tid];
        for (int c = 0; c < 64; ++c) { unsigned h = hist[c][tid]; hist[c][tid] = run; run += h; }
    }
    __syncthreads();
    {
        unsigned* dst = st + ((size_t)B * NHASH + r) * T_LEN;
        const int base = tid * 64;
        for (int k = 0; k < 64; ++k) {
            unsigned bb2 = bkt[base + k];
            unsigned p = hist[tid][bb2]++;
            dst[p] = (unsigned)(base + k);
        }
    }
}

// ------------------------------------------------------------------
// K4a: per-bin logits. 3-term split MFMA S^T with FULL K=128 coverage
// (kt = 0..7, 16 dims per step). lse via 4-way (jt2,h5) LDS merge.
// ------------------------------------------------------------------
__global__ __launch_bounds__(256, 2) void k_bin_lse(
    const __hip_bfloat16* __restrict__ qkh, const __hip_bfloat16* __restrict__ qkl,
    const float* __restrict__ rsn, const unsigned* __restrict__ st,
    float* __restrict__ logitsArr)
{
    __shared__ short Kh[128 * 128];
    __shared__ short Kl2[128 * 128];
    __shared__ int ktok[128];
    __shared__ float rs_l[128];
    __shared__ float red4[2][2][2][32][2];   // [it][jt2][h5][col][{m,s}]

    const int tid = threadIdx.x;
    const int c = blockIdx.x & 63;
    const int r = (blockIdx.x >> 6) & 7;
    const int B = blockIdx.x >> 9;
    const unsigned* stp = st + ((size_t)B * NHASH + r) * T_LEN;

    if (tid < 128) {
        int cc = (tid < 64) ? c : (c == 0 ? 1 : c - 1);
        int tok = (int)stp[cc * 64 + (tid & 63)];
        ktok[tid] = tok;
        rs_l[tid] = rsn[(size_t)B * T_LEN + tok];
    }
    __syncthreads();

    for (int u = tid; u < 128 * 16; u += 256) {
        int row = u >> 4, blk = u & 15;
        size_t gbase = ((size_t)B * T_LEN + ktok[row]) * DH + blk * 8;
        *reinterpret_cast<int4*>(&Kh[swz(row, blk * 8)]) =
            *reinterpret_cast<const int4*>(qkh + gbase);
        *reinterpret_cast<int4*>(&Kl2[swz(row, blk * 8)]) =
            *reinterpret_cast<const int4*>(qkl + gbase);
    }

    const int wave = tid >> 6, lane = tid & 63;
    const int it = wave & 1, jt2 = wave >> 1;
    const int h5 = lane >> 5;

    const int qtok_i = ktok[it * 32 + (lane & 31)];
    short8 qfh[8], qfl[8];
    {
        size_t qoff = ((size_t)B * T_LEN + qtok_i) * DH + (h5 << 3);
        #pragma unroll
        for (int kt = 0; kt < 8; ++kt) {
            qfh[kt] = *reinterpret_cast<const short8*>(qkh + qoff + kt * 16);
            qfl[kt] = *reinterpret_cast<const short8*>(qkl + qoff + kt * 16);
        }
    }
    __syncthreads();

    const float scale = 0.08838834764831845f;  // 128^-0.5
    float sv[32];
    #pragma unroll
    for (int jj = 0; jj < 2; ++jj) {
        int jt = jt2 * 2 + jj;
        f32x16 acc = {};
        #pragma unroll
        for (int kt = 0; kt < 8; ++kt) {        // FULL K: 8 × 16 = 128 dims
            int so = swz(jt * 32 + (lane & 31), kt * 16 + (h5 << 3));
            short8 afh = *reinterpret_cast<const short8*>(&Kh[so]);
            short8 afl = *reinterpret_cast<const short8*>(&Kl2[so]);
            acc = __builtin_amdgcn_mfma_f32_32x32x16_bf16(afh, qfh[kt], acc, 0, 0, 0);
            acc = __builtin_amdgcn_mfma_f32_32x32x16_bf16(afl, qfh[kt], acc, 0, 0, 0);
            acc = __builtin_amdgcn_mfma_f32_32x32x16_bf16(afh, qfl[kt], acc, 0, 0, 0);
        }
        #pragma unroll
        for (int r2 = 0; r2 < 16; ++r2) {
            int jl = (r2 & 3) + ((r2 >> 2) << 3) + (h5 << 2);
            int jf = jt * 32 + jl;
            float s = acc[r2] * (scale * rs_l[jf]);
            sv[jj * 16 + r2] = (ktok[jf] == qtok_i) ? -1e5f : s;
        }
    }
    float m = sv[0];
    #pragma unroll
    for (int u = 1; u < 32; ++u) m = fmaxf(m, sv[u]);
    float s = 0.f;
    #pragma unroll
    for (int u = 0; u < 32; ++u) s += __expf(sv[u] - m);
    red4[it][jt2][h5][lane & 31][0] = m;
    red4[it][jt2][h5][lane & 31][1] = s;
    __syncthreads();
    if (tid < 64) {
        int it2 = tid >> 5, i = tid & 31;
        float bm = -1e30f, bs = 0.f;
        #pragma unroll
        for (int q4 = 0; q4 < 4; ++q4) {
            float pm = red4[it2][q4 >> 1][q4 & 1][i][0];
            float ps = red4[it2][q4 >> 1][q4 & 1][i][1];
            float nm = fmaxf(bm, pm);
            bs = bs * __expf(bm - nm) + ps * __expf(pm - nm);
            bm = nm;
        }
        logitsArr[((size_t)B * NHASH + r) * T_LEN + ktok[it2 * 32 + i]] = bm + logf(bs);
    }
}

// ------------------------------------------------------------------
// K5: LSE over the 8 hash rounds per (B, token) — unchanged.
// ------------------------------------------------------------------
__global__ __launch_bounds__(256) void k_lse(
    const float* __restrict__ logitsArr, float* __restrict__ LSE)
{
    int g = blockIdx.x * 256 + threadIdx.x;
    int B = g >> 12, tok = g & 4095;
    float l[NHASH];
    float m = -1e30f;
    #pragma unroll
    for (int r = 0; r < NHASH; ++r) {
        l[r] = logitsArr[((size_t)B * NHASH + r) * T_LEN + tok];
        m = fmaxf(m, l[r]);
    }
    float s = 0.f;
    #pragma unroll
    for (int r = 0; r < NHASH; ++r) s += expf(l[r] - m);
    LSE[g] = m + logf(s);
}

// ------------------------------------------------------------------
// K4b: per-bin PV. MFMA S^T (full K=128) -> P f32 to LDS by address ->
// V row-major -> scalar f32 PV (proven) -> atomicAdd.
// ------------------------------------------------------------------
__global__ __launch_bounds__(256, 2) void k_bin_pv(
    const __hip_bfloat16* __restrict__ qkh, const __hip_bfloat16* __restrict__ qkl,
    const __hip_bfloat16* __restrict__ vb, const float* __restrict__ rsn,
    const unsigned* __restrict__ st, const float* __restrict__ LSE,
    float* __restrict__ attn)
{
    __shared__ short Kh[128 * 128];        // K_hi during dots, then P f32 [128][64]
    __shared__ short KV[128 * 128];        // K_lo during dots, then V row-major
    __shared__ int ktok[128];
    __shared__ float rs_l[128];

    const int tid = threadIdx.x;
    const int c = blockIdx.x & 63;
    const int r = (blockIdx.x >> 6) & 7;
    const int B = blockIdx.x >> 9;
    const unsigned* stp = st + ((size_t)B * NHASH + r) * T_LEN;

    if (tid < 128) {
        int cc = (tid < 64) ? c : (c == 0 ? 1 : c - 1);
        int tok = (int)stp[cc * 64 + (tid & 63)];
        ktok[tid] = tok;
        rs_l[tid] = rsn[(size_t)B * T_LEN + tok];
    }
    __syncthreads();

    for (int u = tid; u < 128 * 16; u += 256) {
        int row = u >> 4, blk = u & 15;
        size_t gbase = ((size_t)B * T_LEN + ktok[row]) * DH + blk * 8;
        *reinterpret_cast<int4*>(&Kh[swz(row, blk * 8)]) =
            *reinterpret_cast<const int4*>(qkh + gbase);
        *reinterpret_cast<int4*>(&KV[swz(row, blk * 8)]) =
            *reinterpret_cast<const int4*>(qkl + gbase);
    }

    const int wave = tid >> 6, lane = tid & 63;
    const int it = wave & 1, jt2 = wave >> 1;
    const int h5 = lane >> 5;
    const int i_loc = it * 32 + (lane & 31);
    const int qtok_i = ktok[i_loc];
    const float lse_i = LSE[(size_t)B * T_LEN + qtok_i];
    short8 qfh[8], qfl[8];
    {
        size_t qoff = ((size_t)B * T_LEN + qtok_i) * DH + (h5 << 3);
        #pragma unroll
        for (int kt = 0; kt < 8; ++kt) {
            qfh[kt] = *reinterpret_cast<const short8*>(qkh + qoff + kt * 16);
            qfl[kt] = *reinterpret_cast<const short8*>(qkl + qoff + kt * 16);
        }
    }
    __syncthreads();

    const float scale = 0.08838834764831845f;
    float p2[2][16];
    #pragma unroll
    for (int jj = 0; jj < 2; ++jj) {
        int jt = jt2 * 2 + jj;
        f32x16 acc = {};
        #pragma unroll
        for (int kt = 0; kt < 8; ++kt) {        // FULL K: 8 × 16 = 128 dims
            int so = swz(jt * 32 + (lane & 31), kt * 16 + (h5 << 3));
            short8 afh = *reinterpret_cast<const short8*>(&Kh[so]);
            short8 afl = *reinterpret_cast<const short8*>(&KV[so]);
            acc = __builtin_amdgcn_mfma_f32_32x32x16_bf16(afh, qfh[kt], acc, 0, 0, 0);
            acc = __builtin_amdgcn_mfma_f32_32x32x16_bf16(afl, qfh[kt], acc, 0, 0, 0);
            acc = __builtin_amdgcn_mfma_f32_32x32x16_bf16(afh, qfl[kt], acc, 0, 0, 0);
        }
        #pragma unroll
        for (int r2 = 0; r2 < 16; ++r2) {
            int jl = (r2 & 3) + ((r2 >> 2) << 3) + (h5 << 2);
            int jf = jt * 32 + jl;
            float s = acc[r2] * (scale * rs_l[jf]);
            p2[jj][r2] = (ktok[jf] == qtok_i) ? 0.f : __expf(s - lse_i);
        }
    }
    __syncthreads();   // all waves done reading Kh/KV as K_hi/K_lo

    // write P f32 into Kh region: Pl[j][i]
    float* Pl = reinterpret_cast<float*>(Kh);
    #pragma unroll
    for (int jj = 0; jj < 2; ++jj) {
        int jt = jt2 * 2 + jj;
        #pragma unroll
        for (int r2 = 0; r2 < 16; ++r2) {
            int jl = (r2 & 3) + ((r2 >> 2) << 3) + (h5 << 2);
            Pl[(jt * 32 + jl) * 64 + i_loc] = p2[jj][r2];
        }
    }
    // restage KV as V ROW-MAJOR [j][d] bf16
    for (int u = tid; u < 128 * 16; u += 256) {
        int row = u >> 4, blk = u & 15;
        *reinterpret_cast<int4*>(&KV[row * 128 + blk * 8]) =
            *reinterpret_cast<const int4*>(vb + ((size_t)B * T_LEN + ktok[row]) * DH + blk * 8);
    }
    __syncthreads();

    // scalar PV: thread (ig2 = tid>>4 -> 4 queries, dg = tid&15 -> 8 dims)
    const int ig2 = tid >> 4, dg = tid & 15;
    float acc2[4][8];
    #pragma unroll
    for (int a2 = 0; a2 < 4; ++a2)
        #pragma unroll
        for (int b2 = 0; b2 < 8; ++b2) acc2[a2][b2] = 0.f;
    for (int j = 0; j < 128; ++j) {
        float pa[4];
        #pragma unroll
        for (int a2 = 0; a2 < 4; ++a2) pa[a2] = Pl[j * 64 + ig2 * 4 + a2];
        short8 vv = *reinterpret_cast<const short8*>(&KV[j * 128 + dg * 8]);
        #pragma unroll
        for (int b2 = 0; b2 < 8; ++b2) {
            float vf = bfs2f(vv[b2]);
            #pragma unroll
            for (int a2 = 0; a2 < 4; ++a2) acc2[a2][b2] = fmaf(pa[a2], vf, acc2[a2][b2]);
        }
    }
    #pragma unroll
    for (int a2 = 0; a2 < 4; ++a2) {
        int tok = ktok[ig2 * 4 + a2];
        float* dstp = attn + ((size_t)B * T_LEN + tok) * DH + dg * 8;
        #pragma unroll
        for (int b2 = 0; b2 < 8; ++b2) atomicAdd(dstp + b2, acc2[a2][b2]);
    }
}

// ------------------------------------------------------------------
// K6: out = un-merge-heads(attn) @ w_out + b_out — unchanged.
// ------------------------------------------------------------------
__global__ __launch_bounds__(256) void k_out(
    const float* __restrict__ attn, const float* __restrict__ wout,
    const float* __restrict__ bout, float* __restrict__ out)
{
    __shared__ float as_[EMBD];
    const int row = blockIdx.x;
    const int tid = threadIdx.x;
    for (int u = tid; u < EMBD; u += 256) {
        int h = u >> 7, d = u & 127;
        int b = row >> 12, t = row & 4095;
        as_[u] = attn[((size_t)(b * NHEADS + h) * T_LEN + t) * DH + d];
    }
    __syncthreads();
    float a0 = 0, a1 = 0, a2 = 0, a3 = 0;
    const float* wp = wout + 4 * tid;
    #pragma unroll 4
    for (int e = 0; e < EMBD; ++e) {
        float4 w4 = *reinterpret_cast<const float4*>(wp + (size_t)e * EMBD);
        float xe = as_[e];
        a0 = fmaf(xe, w4.x, a0); a1 = fmaf(xe, w4.y, a1);
        a2 = fmaf(xe, w4.z, a2); a3 = fmaf(xe, w4.w, a3);
    }
    int j = 4 * tid;
    float4 o;
    o.x = a0 + bout[j + 0]; o.y = a1 + bout[j + 1];
    o.z = a2 + bout[j + 2]; o.w = a3 + bout[j + 3];
    *reinterpret_cast<float4*>(out + (size_t)row * EMBD + j) = o;
}

// ------------------------------------------------------------------
extern "C" void kernel_launch(void* const* d_in, const int* in_sizes, int n_in,
                              void* d_out, int out_size, void* d_ws, size_t ws_size,
                              hipStream_t stream)
{
    const float* x    = (const float*)d_in[0];
    const float* wqk  = (const float*)d_in[1];
    const float* wv   = (const float*)d_in[2];
    const float* wout = (const float*)d_in[3];
    const float* bout = (const float*)d_in[4];
    const float* rot  = (const float*)d_in[5];
    float* out = (float*)d_out;

    char* ws = (char*)d_ws;
    __hip_bfloat16* qkh       = (__hip_bfloat16*)(ws);              // 16.78 MB
    __hip_bfloat16* qkl       = (__hip_bfloat16*)(ws + 16777216);   // 16.78 MB
    __hip_bfloat16* vb        = (__hip_bfloat16*)(ws + 33554432);   // 16.78 MB
    float*          attn      = (float*)        (ws + 50331648);    // 33.55 MB
    unsigned*       bucketArr = (unsigned*)     (ws + 83886080);    //  2.10 MB
    unsigned*       st        = (unsigned*)     (ws + 85983232);    //  2.10 MB
    float*          logitsArr = (float*)        (ws + 88080384);    //  2.10 MB
    float*          LSE       = (float*)        (ws + 90177536);    //  0.26 MB
    float*          rsn       = (float*)        (ws + 90439680);    //  0.26 MB

    hipMemsetAsync(attn, 0, 33554432, stream);

    k_qk_hash<<<8192, 256, 0, stream>>>(x, wqk, rot, qkh, qkl, rsn, bucketArr);
    k_vproj<<<8192, 256, 0, stream>>>(x, wv, vb);
    k_sort<<<128, 64, 0, stream>>>(bucketArr, st);
    k_bin_lse<<<8192, 256, 0, stream>>>(qkh, qkl, rsn, st, logitsArr);
    k_lse<<<256, 256, 0, stream>>>(logitsArr, LSE);
    k_bin_pv<<<8192, 256, 0, stream>>>(qkh, qkl, vb, rsn, st, LSE, attn);
    k_out<<<8192, 256, 0, stream>>>(attn, wout, bout, out);
}